// Round 8
// baseline (680.143 us; speedup 1.0000x reference)
//
#include <hip/hip_runtime.h>
#include <hip/hip_bf16.h>
#include <stdint.h>

#define BATCH 32
#define CIN 128
#define HH 64
#define WW 64
#define MID 256
#define NCLS 65
#define HI 512
#define NWORDS 8      // 512 cols / 64 bits
#define XP2 72        // patch row stride (halfs), 64 c + 8 pad; 144 B = 16B-aligned
#define HBS2 264      // hb row stride (halfs)
#define SEMS 68       // sem row stride (floats)

typedef _Float16 half8 __attribute__((ext_vector_type(8)));
typedef _Float16 half4v __attribute__((ext_vector_type(4)));
typedef _Float16 half2v __attribute__((ext_vector_type(2)));
typedef float f32x4 __attribute__((ext_vector_type(4)));

// ---------------------------------------------------------------------------
// Pack w1 [m][c][ky][kx] into MFMA A-fragment layout, f16 hi/lo split.
// Index: (((kix*4 + s)*16 + mt)*64 + lane)*8 + j
//   m = mt*16 + (lane&15); c = s*32 + (lane>>4)*8 + j; (ky,kx) = kix/3,kix%3
// Also zeroes the NMS convergence flags (ws is re-poisoned every launch).
// ---------------------------------------------------------------------------
__global__ __launch_bounds__(256) void prep_w1f(
    const float* __restrict__ w1, _Float16* __restrict__ w1fh,
    _Float16* __restrict__ w1fl, int* __restrict__ flags)
{
    const int idx = blockIdx.x * 256 + threadIdx.x;   // < 294912
    if (blockIdx.x == 0 && threadIdx.x < 16) flags[threadIdx.x] = 0;
    const int j = idx & 7, lane = (idx >> 3) & 63, mt = (idx >> 9) & 15;
    const int s = (idx >> 13) & 3, kix = idx >> 15;
    const int m = mt * 16 + (lane & 15);
    const int c = s * 32 + (lane >> 4) * 8 + j;
    const int ky = kix / 3, kx = kix - ky * 3;
    const float v = w1[((m * CIN + c) * 3 + ky) * 3 + kx];
    const _Float16 hi = (_Float16)v;
    w1fh[idx] = hi;
    w1fl[idx] = (_Float16)(v - (float)hi);
}

// ---------------------------------------------------------------------------
// Pack w2 [o][m] into MFMA A-fragment layout (o padded 65->80), f16 hi/lo.
// ---------------------------------------------------------------------------
__global__ __launch_bounds__(256) void prep_w2f(
    const float* __restrict__ w2, _Float16* __restrict__ w2fh,
    _Float16* __restrict__ w2fl)
{
    const int idx = blockIdx.x * 256 + threadIdx.x;   // < 20480
    const int j = idx & 7, lane = (idx >> 3) & 63;
    const int ks = (idx >> 9) & 7, mt = idx >> 12;
    const int o = mt * 16 + (lane & 15);
    const int k = ks * 32 + (lane >> 4) * 8 + j;
    const float v = (o < NCLS) ? w2[o * MID + k] : 0.f;
    const _Float16 hi = (_Float16)v;
    w2fh[idx] = hi;
    w2fl[idx] = (_Float16)(v - (float)hi);
}

// ---------------------------------------------------------------------------
// MFMA head, K-chunked for occupancy: patch staged in 2 chunks of 64
// channels (LDS 28.8 KB -> 4 blocks/CU vs round-7's 54.8 KB -> 2).
// Epilogue in 4x16-pixel quarter passes (hb+sem overlay the patch).
// ---------------------------------------------------------------------------
__global__ __launch_bounds__(256) void head_kernel(
    const float* __restrict__ x,
    const _Float16* __restrict__ w1fh, const _Float16* __restrict__ w1fl,
    const _Float16* __restrict__ w2fh, const _Float16* __restrict__ w2fl,
    const float* __restrict__ b1, const float* __restrict__ b2,
    float* __restrict__ out)
{
    const int b  = blockIdx.z;
    const int y0 = blockIdx.y * 8, x0 = blockIdx.x * 8;
    const int tid = threadIdx.x;
    const int lane = tid & 63, w = tid >> 6;
    const int n = lane & 15, q = lane >> 4;

    __shared__ __align__(16) unsigned char SM[28800];
    _Float16* const xh = (_Float16*)SM;            // [100][XP2]
    _Float16* const xl = xh + 100 * XP2;           // +14400 B
    _Float16* const hbh = (_Float16*)SM;           // [16][HBS2] (overlay)
    _Float16* const hbl = hbh + 16 * HBS2;         // +8448 B
    float* const sem  = (float*)(SM + 16896);      // [16][SEMS]
    float* const rinv = sem + 16 * SEMS;           // 16 floats

    const float* xb = x + (size_t)b * CIN * HH * WW;

    f32x4 acc[4][4];   // [mtile i][ntile t]
#pragma unroll
    for (int i = 0; i < 4; ++i)
#pragma unroll
        for (int t = 0; t < 4; ++t) acc[i][t] = (f32x4){0.f, 0.f, 0.f, 0.f};

    int bposT[4];
#pragma unroll
    for (int t = 0; t < 4; ++t)
        bposT[t] = (t * 2 + (n >> 3)) * 10 + (n & 7);

    for (int ch = 0; ch < 2; ++ch) {
        __syncthreads();
        // stage 64 channels of the 10x10 patch as f16 hi/lo, [pos][c]
        for (int i = tid; i < 3200; i += 256) {
            const int c2 = i / 100, pos = i - c2 * 100;
            const int r = pos / 10, cc = pos - r * 10;
            const int gy = y0 - 1 + r, gx = x0 - 1 + cc;
            const int cg = ch * 64 + c2 * 2;
            float v0 = 0.f, v1 = 0.f;
            if ((unsigned)gy < HH && (unsigned)gx < WW) {
                const float* p = xb + (cg * HH + gy) * WW + gx;
                v0 = p[0]; v1 = p[HH * WW];
            }
            const _Float16 h0 = (_Float16)v0, h1 = (_Float16)v1;
            half2v hi = {h0, h1};
            half2v lo = {(_Float16)(v0 - (float)h0),
                         (_Float16)(v1 - (float)h1)};
            *(half2v*)(xh + pos * XP2 + c2 * 2) = hi;
            *(half2v*)(xl + pos * XP2 + c2 * 2) = lo;
        }
        __syncthreads();
        for (int kix = 0; kix < 9; ++kix) {
            const int ky = kix / 3;
            const int koff = ky * 10 + (kix - ky * 3);
#pragma unroll
            for (int s2 = 0; s2 < 2; ++s2) {
                const int s = ch * 2 + s2;
                half8 Ah[4], Al[4];
#pragma unroll
                for (int i = 0; i < 4; ++i) {
                    const size_t o = (size_t)(kix * 4 + s) * 8192 +
                                     (w * 4 + i) * 512 + lane * 8;
                    Ah[i] = *(const half8*)(w1fh + o);
                    Al[i] = *(const half8*)(w1fl + o);
                }
                half8 Bh[4], Bl[4];
#pragma unroll
                for (int t = 0; t < 4; ++t) {
                    const int a = (bposT[t] + koff) * XP2 + s2 * 32 + q * 8;
                    Bh[t] = *(const half8*)(xh + a);
                    Bl[t] = *(const half8*)(xl + a);
                }
#pragma unroll
                for (int i = 0; i < 4; ++i)
#pragma unroll
                    for (int t = 0; t < 4; ++t) {
                        acc[i][t] = __builtin_amdgcn_mfma_f32_16x16x32_f16(
                            Ah[i], Bh[t], acc[i][t], 0, 0, 0);
                        acc[i][t] = __builtin_amdgcn_mfma_f32_16x16x32_f16(
                            Ah[i], Bl[t], acc[i][t], 0, 0, 0);
                        acc[i][t] = __builtin_amdgcn_mfma_f32_16x16x32_f16(
                            Al[i], Bh[t], acc[i][t], 0, 0, 0);
                    }
            }
        }
    }

    // ---- epilogue: 4 quarter passes of 16 pixels (ntile t) ----
    for (int t = 0; t < 4; ++t) {
        __syncthreads();    // patch / prev-quarter sem dead
        // bias + relu -> hb [p=n][m], f16 hi/lo
#pragma unroll
        for (int i = 0; i < 4; ++i) {
            const int m0 = w * 64 + i * 16 + q * 4;
            const f32x4 a = acc[i][t];
            const float4 bv = *(const float4*)(b1 + m0);
            const float h0 = fmaxf(a[0] + bv.x, 0.f);
            const float h1 = fmaxf(a[1] + bv.y, 0.f);
            const float h2 = fmaxf(a[2] + bv.z, 0.f);
            const float h3 = fmaxf(a[3] + bv.w, 0.f);
            half4v hh = {(_Float16)h0, (_Float16)h1,
                         (_Float16)h2, (_Float16)h3};
            half4v hl = {(_Float16)(h0 - (float)hh[0]),
                         (_Float16)(h1 - (float)hh[1]),
                         (_Float16)(h2 - (float)hh[2]),
                         (_Float16)(h3 - (float)hh[3])};
            *(half4v*)(hbh + n * HBS2 + m0) = hh;
            *(half4v*)(hbl + n * HBS2 + m0) = hl;
        }
        __syncthreads();
        // 1x1 MFMA: M=80 over 5 mtiles, waves get {0,1},{2,3},{4},{}
        {
            const int mtbase = (w == 0) ? 0 : (w == 1) ? 2 : (w == 2) ? 4 : 5;
            const int mtcnt  = (w < 2) ? 2 : (w == 2) ? 1 : 0;
            f32x4 a2[2];
            a2[0] = (f32x4){0.f, 0.f, 0.f, 0.f};
            a2[1] = (f32x4){0.f, 0.f, 0.f, 0.f};
            if (mtcnt) {
#pragma unroll
                for (int ks = 0; ks < 8; ++ks) {
                    const int ad = n * HBS2 + ks * 32 + q * 8;
                    const half8 B2h = *(const half8*)(hbh + ad);
                    const half8 B2l = *(const half8*)(hbl + ad);
#pragma unroll
                    for (int j = 0; j < 2; ++j)
                        if (j < mtcnt) {
                            const size_t o =
                                (size_t)((mtbase + j) * 8 + ks) * 512 +
                                lane * 8;
                            const half8 A2h = *(const half8*)(w2fh + o);
                            const half8 A2l = *(const half8*)(w2fl + o);
                            a2[j] = __builtin_amdgcn_mfma_f32_16x16x32_f16(
                                A2h, B2h, a2[j], 0, 0, 0);
                            a2[j] = __builtin_amdgcn_mfma_f32_16x16x32_f16(
                                A2h, B2l, a2[j], 0, 0, 0);
                            a2[j] = __builtin_amdgcn_mfma_f32_16x16x32_f16(
                                A2l, B2h, a2[j], 0, 0, 0);
                        }
                }
#pragma unroll
                for (int j = 0; j < 2; ++j)
                    if (j < mtcnt) {
                        const int o0 = (mtbase + j) * 16 + q * 4;
#pragma unroll
                        for (int r2 = 0; r2 < 4; ++r2) {
                            const int o = o0 + r2;
                            if (o < NCLS)
                                sem[n * SEMS + o] = a2[j][r2] + b2[o];
                        }
                    }
            }
        }
        __syncthreads();
        // softmax per pixel (16 px, 4 lanes each)
        if (tid < 64) {
            const int p = tid >> 2, q4 = tid & 3;
            const int o0 = q4 * 17;
            const int o1 = (o0 + 17 < NCLS) ? o0 + 17 : NCLS;
            float mx = -1e30f;
            for (int o = o0; o < o1; ++o)
                mx = fmaxf(mx, sem[p * SEMS + o]);
            mx = fmaxf(mx, __shfl_xor(mx, 1));
            mx = fmaxf(mx, __shfl_xor(mx, 2));
            float ssum = 0.f;
            for (int o = o0; o < o1; ++o) {
                float e = __expf(sem[p * SEMS + o] - mx);
                sem[p * SEMS + o] = e;
                ssum += e;
            }
            ssum += __shfl_xor(ssum, 1);
            ssum += __shfl_xor(ssum, 2);
            if (q4 == 0) rinv[p] = 1.f / ssum;
        }
        __syncthreads();
        // shuffle + threshold store (16 px x 64 classes)
        for (int t2 = tid; t2 < 1024; t2 += 256) {
            const int p = t2 >> 6, o = t2 & 63;
            float v = sem[p * SEMS + o] * rinv[p];
            if (!(v >= 0.015f)) v = 0.f;
            const int P = t * 16 + p;
            const int py = P >> 3, px = P & 7;
            const int row = (y0 + py) * 8 + (o >> 3);
            const int col = (x0 + px) * 8 + (o & 7);
            out[((size_t)b * HI + row) * HI + col] = v;
        }
    }
}

// ---------------------------------------------------------------------------
// One NMS iteration, bit-packed masks. Min==nullptr => zero mask => init.
// Convergence: if flagIn says the previous iteration changed nothing, the
// fixed point is reached -> copy Min to Mout and exit. Otherwise compute and
// set *flagOut if this block's output differs from its input.
// ---------------------------------------------------------------------------
__global__ __launch_bounds__(256) void nms_iter(
    const float* __restrict__ S, const uint64_t* __restrict__ Min,
    uint64_t* __restrict__ Mout, const int* __restrict__ flagIn,
    int* __restrict__ flagOut)
{
    const int b = blockIdx.z;
    const int bx = blockIdx.x;
    const int ty = blockIdx.y * 64, tx = bx * 64;
    const int tid = threadIdx.x;

    if (flagIn && flagIn[0] == 0) {   // fixed point: pass-through
        if (tid < 64) {
            const size_t idx = ((size_t)b * HI + ty + tid) * NWORDS + bx;
            Mout[idx] = Min[idx];
        }
        return;
    }

    __shared__ uint64_t smw[80 * 3];
    __shared__ uint64_t hd[80 * 3];
    __shared__ uint64_t sup[72 * 3];
    __shared__ __align__(16) float sfl[72 * 76];
    __shared__ __align__(16) float rm[72 * 64];
    __shared__ int schg;

    if (tid == 0) schg = 0;
    if (tid < 240) {
        const int i = tid / 3, j = tid % 3;
        const int yy = ty - 8 + i;
        const int wj = bx - 1 + j;
        uint64_t v = 0;
        if (Min && (unsigned)yy < HI && (unsigned)wj < NWORDS)
            v = Min[((size_t)b * HI + yy) * NWORDS + wj];
        smw[tid] = v;
    }
    __syncthreads();
    if (tid < 240) {
        const int i = tid / 3, j = tid % 3;
        const uint64_t c = smw[i * 3 + j];
        const uint64_t l = j > 0 ? smw[i * 3 + j - 1] : 0ull;
        const uint64_t r = j < 2 ? smw[i * 3 + j + 1] : 0ull;
        uint64_t d = c;
#pragma unroll
        for (int s = 1; s <= 4; ++s)
            d |= (c >> s) | (r << (64 - s)) | (c << s) | (l >> (64 - s));
        hd[tid] = d;
    }
    __syncthreads();
    if (tid < 216) {
        const int r = tid / 3, j = tid % 3;
        uint64_t v = 0;
#pragma unroll
        for (int k = 0; k < 9; ++k) v |= hd[(r + k) * 3 + j];
        sup[tid] = v;
    }
    __syncthreads();
    const float* Sb = S + (size_t)b * HI * HI;
    for (int k = tid; k < 72 * 18; k += 256) {
        const int r = k / 18, f4 = k % 18;
        const int gy = ty - 4 + r;
        const int gx0 = tx - 4 + f4 * 4;
        float4 v = make_float4(0.f, 0.f, 0.f, 0.f);
        float* pv = (float*)&v;
        if ((unsigned)gy < HI) {
            if (gx0 >= 0 && gx0 + 3 < HI)
                v = *(const float4*)(Sb + (size_t)gy * HI + gx0);
            else {
#pragma unroll
                for (int cc = 0; cc < 4; ++cc)
                    if ((unsigned)(gx0 + cc) < HI)
                        pv[cc] = Sb[(size_t)gy * HI + gx0 + cc];
            }
        }
        const int rel64 = 60 + 4 * f4;
        const uint64_t w = sup[r * 3 + (rel64 >> 6)];
        const int b0 = rel64 & 63;
#pragma unroll
        for (int cc = 0; cc < 4; ++cc)
            if ((w >> (b0 + cc)) & 1ull) pv[cc] = 0.f;
        *(float4*)(sfl + r * 76 + f4 * 4) = v;
    }
    __syncthreads();
    for (int k = tid; k < 72 * 16; k += 256) {
        const int r = k / 16, x4 = (k % 16) * 4;
        const float4 a  = *(const float4*)(sfl + r * 76 + x4);
        const float4 bq = *(const float4*)(sfl + r * 76 + x4 + 4);
        const float4 cq = *(const float4*)(sfl + r * 76 + x4 + 8);
        const float v0=a.x,v1=a.y,v2=a.z,v3=a.w;
        const float v4=bq.x,v5=bq.y,v6=bq.z,v7=bq.w;
        const float v8=cq.x,v9=cq.y,v10=cq.z,v11=cq.w;
        const float m4567 = fmaxf(fmaxf(v4,v5), fmaxf(v6,v7));
        const float m23 = fmaxf(v2,v3), m89 = fmaxf(v8,v9);
        const float o0 = fmaxf(fmaxf(fmaxf(v0,v1), m23), fmaxf(m4567, v8));
        const float o1 = fmaxf(fmaxf(v1, m23), fmaxf(m4567, m89));
        const float o2 = fmaxf(fmaxf(m23, m4567), fmaxf(m89, v10));
        const float o3 = fmaxf(fmaxf(v3, m4567), fmaxf(fmaxf(m89, v10), v11));
        *(float4*)(rm + r * 64 + x4) = make_float4(o0,o1,o2,o3);
    }
    __syncthreads();
    {
        const int wv = tid >> 6, lane = tid & 63;
        const int ybase = wv * 16;
        bool chg = false;
        float ring[9];
#pragma unroll
        for (int k = 0; k < 8; ++k) ring[k] = rm[(ybase + k) * 64 + lane];
#pragma unroll
        for (int qq = 0; qq < 16; ++qq) {
            const int y = ybase + qq;
            ring[(qq + 8) % 9] = rm[(y + 8) * 64 + lane];
            float mv = ring[0];
#pragma unroll
            for (int k = 1; k < 9; ++k) mv = fmaxf(mv, ring[k]);
            const float c = sfl[(y + 4) * 76 + lane + 4];
            const uint64_t oldw = smw[(y + 8) * 3 + 1];
            const bool keep = ((oldw >> lane) & 1ull) || (c == mv && c > 0.f);
            const uint64_t word = __ballot(keep);
            if (lane == 0) {
                Mout[((size_t)b * HI + ty + y) * NWORDS + bx] = word;
                chg |= (word != oldw);
            }
        }
        if (lane == 0 && chg) schg = 1;
    }
    __syncthreads();
    if (tid == 0 && schg) atomicOr(flagOut, 1);
}

// ---------------------------------------------------------------------------
// Finalize: out = (Mbit && border) ? S : 0, in place on d_out.
// ---------------------------------------------------------------------------
__global__ __launch_bounds__(256) void finalize_bits(
    float* __restrict__ S, const uint64_t* __restrict__ Mw)
{
    const int i4 = blockIdx.x * 256 + threadIdx.x;
    const size_t base = (size_t)i4 * 4;
    const int x = (int)(base & 511);
    const int y = (int)((base >> 9) & 511);
    const int bb = (int)(base >> 18);
    const uint64_t w = Mw[((size_t)bb * HI + y) * NWORDS + (x >> 6)];
    float4 v = ((const float4*)S)[i4];
    float* pv = (float*)&v;
    const bool rowok = (y >= 4) && (y < HI - 4);
#pragma unroll
    for (int cc = 0; cc < 4; ++cc) {
        const int xx = x + cc;
        const bool keep = rowok && (xx >= 4) && (xx < HI - 4) &&
                          ((w >> (xx & 63)) & 1ull);
        if (!keep) pv[cc] = 0.f;
    }
    ((float4*)S)[i4] = v;
}

extern "C" void kernel_launch(void* const* d_in, const int* in_sizes, int n_in,
                              void* d_out, int out_size, void* d_ws, size_t ws_size,
                              hipStream_t stream) {
    const float* x  = (const float*)d_in[0];
    const float* w1 = (const float*)d_in[1];
    const float* b1 = (const float*)d_in[2];
    const float* w2 = (const float*)d_in[3];
    const float* b2 = (const float*)d_in[4];
    float* out = (float*)d_out;

    // ws: w1f_hi | w1f_lo | w2f_hi | w2f_lo | MA | MB | flags
    char* wsb = (char*)d_ws;
    _Float16* w1fh = (_Float16*)(wsb);
    _Float16* w1fl = (_Float16*)(wsb + 0x90000);
    _Float16* w2fh = (_Float16*)(wsb + 0x120000);
    _Float16* w2fl = (_Float16*)(wsb + 0x130000);
    uint64_t* MA   = (uint64_t*)(wsb + 0x140000);
    uint64_t* MB   = (uint64_t*)(wsb + 0x240000);
    int* flags     = (int*)(wsb + 0x340000);

    prep_w1f<<<294912 / 256, 256, 0, stream>>>(w1, w1fh, w1fl, flags);
    prep_w2f<<<20480 / 256, 256, 0, stream>>>(w2, w2fh, w2fl);
    head_kernel<<<dim3(8, 8, BATCH), 256, 0, stream>>>(
        x, w1fh, w1fl, w2fh, w2fl, b1, b2, out);

    dim3 g(NWORDS, 8, BATCH);
    uint64_t* bufs[2] = {MA, MB};
    nms_iter<<<g, 256, 0, stream>>>(out, nullptr, MA, nullptr, flags + 0);
    for (int it = 1; it <= 8; ++it)
        nms_iter<<<g, 256, 0, stream>>>(out, bufs[(it + 1) & 1], bufs[it & 1],
                                        flags + it - 1, flags + it);
    const int nf4 = BATCH * HI * HI / 4;
    finalize_bits<<<nf4 / 256, 256, 0, stream>>>(out, MA);
}